// Round 5
// baseline (311.859 us; speedup 1.0000x reference)
//
#include <hip/hip_runtime.h>
#include <hip/hip_bf16.h>
#include <stdint.h>

// SNN readout, fused, R5: barrier-free GEMM k-loop with direct global->VGPR
// fragment loads (2-step named prefetch). R4 post-mortem: 1 block/CU + a
// barrier+vmcnt-drain every k-step left all pipes idle (MfmaUtil 5%, VALU 15%,
// HBM 12.5%) -> 133us vs ~30us floor. Waves read disjoint A rows (mq) and W
// halves (nh), so LDS staging was never needed: now only Hs/St/Carry live in
// LDS (38KB), barriers exist only around the per-chunk scan phases (32 total
// vs 160), and the compiler emits precise counted vmcnt for the register
// loads (no GLD16 -> no forced vmcnt(0) drains).
//   flt_t = ALPHA*flt_{t-1} + h_t ;  out_t = BETA*out_{t-1} + flt_{t-1}

#define ALPHA 0.95f
#define BETA  0.9f

constexpr int Bdim = 64, T = 1000, Idim = 512, Odim = 256;
constexpr int TC = 128;            // t-rows per chunk
constexpr int NC = 8;              // chunks per b (7 full + 104-row tail)
constexpr int KS = Idim / 32;      // 16 k-steps per chunk (K=512, BK=32)
constexpr int KK = NC * KS;        // 128 global k-steps
constexpr int HP = 66;             // Hs pitch (fp32): quad offset 8 banks, 2-way max

typedef short bf16x8 __attribute__((ext_vector_type(8)));
typedef float f32x4  __attribute__((ext_vector_type(4)));

constexpr double dpow(double x, int n) { double r = 1; for (int i = 0; i < n; ++i) r *= x; return r; }

// pack 8 fp32 (k-order) -> bf16x8 fragment via HW v_cvt_pk_bf16_f32 (RNE)
__device__ inline bf16x8 cvt8(float4 x0, float4 x1) {
  union { __hip_bfloat162 h[4]; bf16x8 v; } r;
  r.h[0] = __float22bfloat162_rn(make_float2(x0.x, x0.y));
  r.h[1] = __float22bfloat162_rn(make_float2(x0.z, x0.w));
  r.h[2] = __float22bfloat162_rn(make_float2(x1.x, x1.y));
  r.h[3] = __float22bfloat162_rn(make_float2(x1.z, x1.w));
  return r.v;
}

// grid 256 = (og 4) x (b_hi 8) x (b_lo 8); p%8 = b_lo keeps the 4 og-blocks
// of one b on one XCD -> A re-reads (x4) hit that XCD's L2, not HBM/L3.
__global__ __launch_bounds__(512) void fused(const float* __restrict__ A,
                                             const float* __restrict__ W,
                                             float* __restrict__ Out) {
  __shared__ float  Hs[TC * HP];     // 33.8 KB fp32 h chunk
  __shared__ float2 St[8][64];       // subchunk scan states (4 KB)
  __shared__ float2 Carry[64];       // (flt,out) carry across chunks

  const int tid  = threadIdx.x;
  const int lane = tid & 63;
  const int w    = tid >> 6;          // wave 0..7
  const int l15  = lane & 15;
  const int quad = lane >> 4;
  const int mq   = w & 3;             // m-quadrant: rows mq*32..+32
  const int nh   = w >> 2;            // n-half:    cols nh*32..+32

  const int p  = blockIdx.x;
  const int b  = ((p >> 3) & 7) * 8 + (p & 7);
  const int og = p >> 6;              // 0..3

  // per-lane fragment geometry (identical math to the R4-passed kernel):
  // A frag (mt): row m = mq*32 + mt*16 + l15, k = i*32 + quad*8 .. +8
  // W frag (nt): row n = og*64 + nh*32 + nt*16 + l15, same k window
  const int m0 = mq * 32 + l15;       // mt=0 row (local in chunk)
  const int m1 = m0 + 16;             // mt=1 row
  const float* Abase = A + (size_t)b * T * Idim + quad * 8;
  const float* Wp0 = W + (size_t)(og * 64 + nh * 32 + l15) * Idim + quad * 8;
  const float* Wp1 = Wp0 + (size_t)16 * Idim;

  float4 Ar[2][4];                    // [parity][mt*2+half] fp32 prefetch regs
  float4 Wr[2][4];                    // [parity][nt*2+half]

  // load step kk (global 0..127) into parity slot s (indices static-unrolled)
#define LOADA(s_, kk_) do {                                                    \
    const int pf_ = (kk_);                                                     \
    const int kf_ = (pf_ & 15) * 32;                                           \
    int t0_ = (pf_ >> 4) * TC + m0; if (t0_ > T - 1) t0_ = T - 1;              \
    int t1_ = (pf_ >> 4) * TC + m1; if (t1_ > T - 1) t1_ = T - 1;              \
    const float* pa0_ = Abase + (size_t)t0_ * Idim + kf_;                      \
    const float* pa1_ = Abase + (size_t)t1_ * Idim + kf_;                      \
    Ar[s_][0] = *(const float4*)pa0_; Ar[s_][1] = *(const float4*)(pa0_ + 4);  \
    Ar[s_][2] = *(const float4*)pa1_; Ar[s_][3] = *(const float4*)(pa1_ + 4);  \
  } while (0)
#define LOADW(s_, kk_) do {                                                    \
    const int kf_ = ((kk_) & 15) * 32;                                         \
    Wr[s_][0] = *(const float4*)(Wp0 + kf_);                                   \
    Wr[s_][1] = *(const float4*)(Wp0 + kf_ + 4);                               \
    Wr[s_][2] = *(const float4*)(Wp1 + kf_);                                   \
    Wr[s_][3] = *(const float4*)(Wp1 + kf_ + 4);                               \
  } while (0)

  // prime the 2-deep pipeline
  LOADA(0, 0); LOADW(0, 0);
  LOADA(1, 1); LOADW(1, 1);

  if (tid < 64) Carry[tid] = make_float2(0.f, 0.f);
  __syncthreads();                    // Carry visible (once)

  constexpr float AL = (float)dpow(0.95, 16);
  constexpr float BL = (float)dpow(0.90, 16);
  constexpr float WL = (float)((dpow(0.95, 16) - dpow(0.90, 16)) / (0.95 - 0.90));

  for (int c = 0; c < NC; ++c) {
    f32x4 acc[2][2] = {};
    // ---- GEMM k-loop: 16 steps, NO barriers, 2-deep register prefetch ----
#pragma unroll
    for (int i = 0; i < KS; ++i) {
      const int par = i & 1;          // compile-time constant under unroll
      bf16x8 af0 = cvt8(Ar[par][0], Ar[par][1]);
      bf16x8 af1 = cvt8(Ar[par][2], Ar[par][3]);
      bf16x8 bf0 = cvt8(Wr[par][0], Wr[par][1]);
      bf16x8 bf1 = cvt8(Wr[par][2], Wr[par][3]);
      int pf = c * KS + i + 2; if (pf > KK - 1) pf = KK - 1;  // tail: benign dup
      LOADA(par, pf); LOADW(par, pf); // refill same slot (WAR on regs, safe)
      acc[0][0] = __builtin_amdgcn_mfma_f32_16x16x32_bf16(af0, bf0, acc[0][0], 0, 0, 0);
      acc[0][1] = __builtin_amdgcn_mfma_f32_16x16x32_bf16(af0, bf1, acc[0][1], 0, 0, 0);
      acc[1][0] = __builtin_amdgcn_mfma_f32_16x16x32_bf16(af1, bf0, acc[1][0], 0, 0, 0);
      acc[1][1] = __builtin_amdgcn_mfma_f32_16x16x32_bf16(af1, bf1, acc[1][1], 0, 0, 0);
    }

    // ---- epilogue: acc -> Hs (fp32). D layout: col=l15, row=quad*4+r ----
#pragma unroll
    for (int mt = 0; mt < 2; ++mt)
#pragma unroll
      for (int nt = 0; nt < 2; ++nt)
#pragma unroll
        for (int r = 0; r < 4; ++r) {
          const int tl = mq * 32 + mt * 16 + quad * 4 + r;
          const int o  = nh * 32 + nt * 16 + l15;
          Hs[tl * HP + o] = acc[mt][nt][r];
        }
    __syncthreads();

    // ---- scan phase 1: thread (sc=w, o=lane) local-scans 16 steps ----
    {
      const int sc = w, o = lane;
      float f = 0.f, u = 0.f;
#pragma unroll
      for (int j = 0; j < 16; ++j) {
        float h = Hs[(sc * 16 + j) * HP + o];
        float nu = BETA * u + f; f = ALPHA * f + h; u = nu;
      }
      St[sc][o] = make_float2(f, u);
    }
    __syncthreads();

    // ---- phase 2: combine 8 subchunks with persistent carry (wave 0) ----
    if (tid < 64) {
      float2 cv = Carry[tid];
      float f = cv.x, u = cv.y;
#pragma unroll
      for (int cc2 = 0; cc2 < 8; ++cc2) {
        float2 s = St[cc2][tid];
        St[cc2][tid] = make_float2(f, u);          // becomes subchunk init
        float nu = BL * u + WL * f + s.y;          // M^16 carry composition
        f = AL * f + s.x;
        u = nu;
      }
      Carry[tid] = make_float2(f, u);
    }
    __syncthreads();

    // ---- phase 3: rescan with inits, write Out (coalesced 4B/lane) ----
    {
      const int sc = w, o = lane;
      float2 s = St[sc][o];
      float f = s.x, u = s.y;
      const int tb = c * TC + sc * 16;
      float* op = Out + ((size_t)b * T + tb) * Odim + og * 64 + o;
#pragma unroll
      for (int j = 0; j < 16; ++j) {
        float h = Hs[(sc * 16 + j) * HP + o];
        float ov = BETA * u + f; f = ALPHA * f + h; u = ov;
        if (tb + j < T) op[j * Odim] = ov;
      }
    }
    __syncthreads();   // waves drift: protect Hs from next chunk's epilogue
  }
#undef LOADA
#undef LOADW
}

extern "C" void kernel_launch(void* const* d_in, const int* in_sizes, int n_in,
                              void* d_out, int out_size, void* d_ws, size_t ws_size,
                              hipStream_t stream) {
  (void)in_sizes; (void)n_in; (void)d_ws; (void)ws_size; (void)out_size;
  const float* A = (const float*)d_in[0];   // (B, T, I) fp32
  const float* W = (const float*)d_in[1];   // (O, I) fp32
  float* Out = (float*)d_out;               // (B, T, O) fp32
  fused<<<Bdim * 4, 512, 0, stream>>>(A, W, Out);
}

// Round 6
// 240.254 us; speedup vs baseline: 1.2980x; 1.2980x over previous
//
#include <hip/hip_runtime.h>
#include <hip/hip_bf16.h>
#include <stdint.h>

// SNN readout: h = inputs @ W^T (bf16 MFMA), then linear scan over T.
//   flt_t = ALPHA*flt_{t-1} + h_t ;  out_t = BETA*out_{t-1} + flt_{t-1}
// R6: back to the R0 3-kernel structure (fusion disproven: R4 133us / R5
// 171us, both latency-bound at 1 block/CU). One change vs R0: GEMM tile
// 128x256 -> 128x128, grid 500 -> 1000, launch_bounds(256,3): ~3 blocks/CU
// so co-resident blocks overlap each other's per-k-step vmcnt(0)+barrier
// drains (m114 wave-overlap). XCD-chunked swizzle keeps both n-halves of an
// m-tile on one XCD (A-tile fetched once). wconv/scan_all verbatim from R0.

#define ALPHA 0.95f
#define BETA  0.9f

constexpr int Bdim = 64, T = 1000, Idim = 512, Odim = 256;
constexpr int M = Bdim * T;         // 64000 rows
constexpr int C = 40, L = 25;       // T = C*L

typedef short bf16x8 __attribute__((ext_vector_type(8)));
typedef float f32x4  __attribute__((ext_vector_type(4)));

__device__ inline uint32_t pk_bf16(float a, float b) {   // RNE pack
  union { float f; uint32_t u; } x, y; x.f = a; y.f = b;
  uint32_t lo = (x.u + 0x7FFFu + ((x.u >> 16) & 1u)) >> 16;
  uint32_t hi = (y.u + 0x7FFFu + ((y.u >> 16) & 1u)) & 0xFFFF0000u;
  return lo | hi;
}
__device__ inline uint16_t f2bf(float a) {
  union { float f; uint32_t u; } x; x.f = a;
  return (uint16_t)((x.u + 0x7FFFu + ((x.u >> 16) & 1u)) >> 16);
}
__device__ inline float bf2f(uint16_t h) {
  union { uint32_t u; float f; } x; x.u = ((uint32_t)h) << 16;
  return x.f;
}

// async 16B global->LDS (wave-uniform LDS base + lane*16)
#define GLD16(g, l) __builtin_amdgcn_global_load_lds(                         \
    (const __attribute__((address_space(1))) uint32_t*)(g),                   \
    (__attribute__((address_space(3))) uint32_t*)(l), 16, 0, 0)

// pack 8 fp32 (k-order) -> bf16x8 fragment via HW v_cvt_pk_bf16_f32
__device__ inline bf16x8 cvt8(float4 x0, float4 x1) {
  union { __hip_bfloat162 h[4]; bf16x8 v; } r;
  r.h[0] = __float22bfloat162_rn(make_float2(x0.x, x0.y));
  r.h[1] = __float22bfloat162_rn(make_float2(x0.z, x0.w));
  r.h[2] = __float22bfloat162_rn(make_float2(x1.x, x1.y));
  r.h[3] = __float22bfloat162_rn(make_float2(x1.z, x1.w));
  return r.v;
}

// -------- K0: W fp32 -> bf16 (RNE), 131072 elems --------
__global__ __launch_bounds__(256) void wconv(const float* __restrict__ W,
                                             uint16_t* __restrict__ Wbf) {
  int i = (blockIdx.x * 256 + threadIdx.x) * 8;
  float4 a = *(const float4*)(W + i);
  float4 b = *(const float4*)(W + i + 4);
  *(uint4*)(Wbf + i) = make_uint4(pk_bf16(a.x, a.y), pk_bf16(a.z, a.w),
                                  pk_bf16(b.x, b.y), pk_bf16(b.z, b.w));
}

// -------- K1: GEMM H[m][n] = sum_k A[m][k]*W[n][k], 128x128 tile --------
// grid 1000 = 500 m-tiles x 2 n-halves, XCD-chunk swizzled (1000%8==0).
// 256 thr / 4 waves. Wave w: n-range [bn + w*32, +32), all 128 m.
// LDS: As fp32 128x32 (128B rows, 8 chunks of 16B; chunk g at slot g^(row&7));
//      Bs bf16 128x32 (64B rows, 4 chunks;           chunk g at slot g^(row&3)).
__global__ __launch_bounds__(256, 3) void gemm_h(const float* __restrict__ A,
                                                 const uint16_t* __restrict__ Wbf,
                                                 uint16_t* __restrict__ H) {
  __shared__ float    As[128 * 32];   // 16 KB
  __shared__ uint16_t Bs[128 * 32];   // 8 KB

  const int tid  = threadIdx.x;
  const int lane = tid & 63;
  const int w    = tid >> 6;
  const int l15  = lane & 15;
  const int quad = lane >> 4;

  // XCD-chunked bijective swizzle: consecutive logical blocks (same m-tile,
  // both n-halves) land on the same XCD -> shared A-tile L2 hits.
  const int bx = blockIdx.x;
  const int lb = (bx & 7) * 125 + (bx >> 3);
  const int rm = (lb >> 1) * 128;     // m-tile base
  const int bn = (lb & 1) * 128;      // n-half base

  // ---- staging source addresses (swizzle folded into global address) ----
  // A: 4 calls/wave, call i: rows w*32 + i*8 + (lane>>3); slot lane&7 holds
  //    global chunk g = (lane&7) ^ (row&7); 16B = 4 fp32.
  const float* asrc[4];
  char*        aldst[4];
#pragma unroll
  for (int i = 0; i < 4; ++i) {
    int row = w * 32 + i * 8 + (lane >> 3);
    int g   = (lane & 7) ^ (row & 7);
    asrc[i]  = A + (size_t)(rm + row) * Idim + g * 4;
    aldst[i] = (char*)As + w * 4096 + i * 1024;
  }
  // B: 2 calls/wave, call i: rows w*32 + i*16 + (lane>>2); slot lane&3 holds
  //    chunk g = (lane&3) ^ (row&3); 16B = 8 bf16.
  const uint16_t* bsrc[2];
  char*           bldst[2];
#pragma unroll
  for (int i = 0; i < 2; ++i) {
    int row = w * 32 + i * 16 + (lane >> 2);
    int g   = (lane & 3) ^ (row & 3);
    bsrc[i]  = Wbf + (size_t)(bn + row) * Idim + g * 8;
    bldst[i] = (char*)Bs + w * 2048 + i * 1024;
  }

  f32x4 acc[8][2] = {};

  for (int k0 = 0; k0 < Idim; k0 += 32) {
    __syncthreads();                       // prev iter's ds_reads done
#pragma unroll
    for (int i = 0; i < 4; ++i) GLD16(asrc[i] + k0, aldst[i]);
#pragma unroll
    for (int i = 0; i < 2; ++i) GLD16(bsrc[i] + k0, bldst[i]);
    __syncthreads();                       // vmcnt(0) drain + barrier

    // B fragments: local n = w*32 + nt*16 + l15, chunk quad at slot quad^(n&3)
    bf16x8 bfr[2];
#pragma unroll
    for (int nt = 0; nt < 2; ++nt) {
      int n = w * 32 + nt * 16 + l15;
      bfr[nt] = *(const bf16x8*)&Bs[n * 32 + ((quad ^ (n & 3)) * 8)];
    }
    // A fragments: m = mt*16 + l15, chunks {2q,2q+1} at slots (2q)^(m&7), s^1
    bf16x8 af[8];
#pragma unroll
    for (int mt = 0; mt < 8; ++mt) {
      int m  = mt * 16 + l15;
      int s0 = (2 * quad) ^ (m & 7);
      float4 x0 = *(const float4*)&As[m * 32 + s0 * 4];
      float4 x1 = *(const float4*)&As[m * 32 + (s0 ^ 1) * 4];
      af[mt] = cvt8(x0, x1);
      // slot s0 holds chunk 2q, slot s0^1 holds chunk 2q+1 (since
      // (2q^x)^1 == (2q+1)^x for the low bit) -> x0 = k[8q..8q+3], x1 = k[8q+4..]
    }
#pragma unroll
    for (int mt = 0; mt < 8; ++mt)
#pragma unroll
      for (int nt = 0; nt < 2; ++nt)
        acc[mt][nt] = __builtin_amdgcn_mfma_f32_16x16x32_bf16(af[mt], bfr[nt], acc[mt][nt], 0, 0, 0);
  }

  // epilogue: C/D layout col = lane&15, row = quad*4 + reg
#pragma unroll
  for (int mt = 0; mt < 8; ++mt)
#pragma unroll
    for (int nt = 0; nt < 2; ++nt)
#pragma unroll
      for (int r = 0; r < 4; ++r) {
        int gm = rm + mt * 16 + quad * 4 + r;
        int gn = bn + w * 32 + nt * 16 + l15;
        H[(size_t)gm * Odim + gn] = f2bf(acc[mt][nt][r]);
      }
}

// -------- K2: whole scan in one kernel, h kept in registers --------
// grid 256 = (b, og): block owns 64 o's, all T. 640 thr: c = tid>>4 (40),
// ol = tid&15 (4 o's). Phase1 local scan (h -> regs) -> St(LDS); phase2
// in-LDS combine; phase3 rescan from registers, write Out.
constexpr double dpow(double x, int n) { double r = 1.0; for (int i = 0; i < n; ++i) r *= x; return r; }

__global__ __launch_bounds__(640) void scan_all(const uint16_t* __restrict__ H,
                                                float* __restrict__ Out) {
  constexpr float AL = (float)dpow(0.95, L);
  constexpr float BL = (float)dpow(0.90, L);
  constexpr float WL = (float)((dpow(0.95, L) - dpow(0.90, L)) / (0.95 - 0.90));
  __shared__ float2 St[C][64];

  const int b   = blockIdx.x >> 2;
  const int og  = blockIdx.x & 3;
  const int tid = threadIdx.x;
  const int c   = tid >> 4;
  const int ol  = tid & 15;

  const size_t base = ((size_t)b * T + c * L) * Odim + og * 64 + ol * 4;
  const ushort4* hp = (const ushort4*)(H + base);

  ushort4 hv[L];                        // 25 x 8B = 50 VGPRs, read H once
  // phase 1: local scan, zero init
  {
    float f[4] = {}, u[4] = {};
#pragma unroll
    for (int j = 0; j < L; ++j) {
      hv[j] = hp[j * 64];
      float h0 = bf2f(hv[j].x), h1 = bf2f(hv[j].y), h2 = bf2f(hv[j].z), h3 = bf2f(hv[j].w);
      float n0 = BETA * u[0] + f[0]; f[0] = ALPHA * f[0] + h0; u[0] = n0;
      float n1 = BETA * u[1] + f[1]; f[1] = ALPHA * f[1] + h1; u[1] = n1;
      float n2 = BETA * u[2] + f[2]; f[2] = ALPHA * f[2] + h2; u[2] = n2;
      float n3 = BETA * u[3] + f[3]; f[3] = ALPHA * f[3] + h3; u[3] = n3;
    }
#pragma unroll
    for (int i = 0; i < 4; ++i) St[c][ol * 4 + i] = make_float2(f[i], u[i]);
  }
  __syncthreads();

  // phase 2: combine across chunks in place (St[c] becomes that chunk's init)
  if (tid < 64) {
    float f = 0.f, u = 0.f;
#pragma unroll
    for (int cc = 0; cc < C; ++cc) {
      float2 s = St[cc][tid];
      St[cc][tid] = make_float2(f, u);
      float nu = BL * u + WL * f + s.y;   // uses old f
      f = AL * f + s.x;
      u = nu;
    }
  }
  __syncthreads();

  // phase 3: rescan from registers with chunk inits, write Out
  {
    float f[4], u[4];
#pragma unroll
    for (int i = 0; i < 4; ++i) { float2 s = St[c][ol * 4 + i]; f[i] = s.x; u[i] = s.y; }
    float4* op = (float4*)(Out + base);
#pragma unroll
    for (int j = 0; j < L; ++j) {
      float h0 = bf2f(hv[j].x), h1 = bf2f(hv[j].y), h2 = bf2f(hv[j].z), h3 = bf2f(hv[j].w);
      float4 o4;
      o4.x = BETA * u[0] + f[0]; f[0] = ALPHA * f[0] + h0; u[0] = o4.x;
      o4.y = BETA * u[1] + f[1]; f[1] = ALPHA * f[1] + h1; u[1] = o4.y;
      o4.z = BETA * u[2] + f[2]; f[2] = ALPHA * f[2] + h2; u[2] = o4.z;
      o4.w = BETA * u[3] + f[3]; f[3] = ALPHA * f[3] + h3; u[3] = o4.w;
      op[j * 64] = o4;
    }
  }
}

extern "C" void kernel_launch(void* const* d_in, const int* in_sizes, int n_in,
                              void* d_out, int out_size, void* d_ws, size_t ws_size,
                              hipStream_t stream) {
  const float* A = (const float*)d_in[0];   // (B, T, I) fp32
  const float* W = (const float*)d_in[1];   // (O, I) fp32
  float* Out = (float*)d_out;               // (B, T, O) fp32

  // workspace: H (bf16, 32.77MB) | Wbf (bf16, 0.25MB)
  uint16_t* H   = (uint16_t*)d_ws;
  uint16_t* Wbf = H + (size_t)M * Odim;

  wconv<<<Odim * Idim / (256 * 8), 256, 0, stream>>>(W, Wbf);
  gemm_h<<<(M / 128) * 2, 256, 0, stream>>>(A, Wbf, H);
  scan_all<<<Bdim * 4, 640, 0, stream>>>(H, Out);
}

// Round 7
// 229.264 us; speedup vs baseline: 1.3603x; 1.0479x over previous
//
#include <hip/hip_runtime.h>
#include <hip/hip_bf16.h>
#include <stdint.h>

// SNN readout: h = inputs @ W^T (bf16 MFMA), then linear scan over T.
//   flt_t = ALPHA*flt_{t-1} + h_t ;  out_t = BETA*out_{t-1} + flt_{t-1}
// R7: R0 structure (best, 226.7us; R6's 128x128 split regressed to 240.3).
// ONE change vs R0's gemm: double-buffered LDS + counted-vmcnt 2-phase ring.
// R0's k-loop drained vmcnt(0) at every step (bursty DMA, ~2.7 TB/s, 60us).
// Now STAGE(t+1) stays in flight across both barriers (vmcnt(8) retires only
// step t's 8 loads) -> continuous DMA issue, tail latency amortized (T3/T4,
// m218). LDS 32->64KB, still 2 blocks/CU. wconv/scan_all verbatim from R0.

#define ALPHA 0.95f
#define BETA  0.9f

constexpr int Bdim = 64, T = 1000, Idim = 512, Odim = 256;
constexpr int M = Bdim * T;         // 64000 rows
constexpr int C = 40, L = 25;       // T = C*L

typedef short bf16x8 __attribute__((ext_vector_type(8)));
typedef float f32x4  __attribute__((ext_vector_type(4)));

__device__ inline uint32_t pk_bf16(float a, float b) {   // RNE pack
  union { float f; uint32_t u; } x, y; x.f = a; y.f = b;
  uint32_t lo = (x.u + 0x7FFFu + ((x.u >> 16) & 1u)) >> 16;
  uint32_t hi = (y.u + 0x7FFFu + ((y.u >> 16) & 1u)) & 0xFFFF0000u;
  return lo | hi;
}
__device__ inline uint16_t f2bf(float a) {
  union { float f; uint32_t u; } x; x.f = a;
  return (uint16_t)((x.u + 0x7FFFu + ((x.u >> 16) & 1u)) >> 16);
}
__device__ inline float bf2f(uint16_t h) {
  union { uint32_t u; float f; } x; x.u = ((uint32_t)h) << 16;
  return x.f;
}

// async 16B global->LDS (wave-uniform LDS base + lane*16)
#define GLD16(g, l) __builtin_amdgcn_global_load_lds(                         \
    (const __attribute__((address_space(1))) uint32_t*)(g),                   \
    (__attribute__((address_space(3))) uint32_t*)(l), 16, 0, 0)

// pack 8 fp32 (k-order) -> bf16x8 fragment via HW v_cvt_pk_bf16_f32
__device__ inline bf16x8 cvt8(float4 x0, float4 x1) {
  union { __hip_bfloat162 h[4]; bf16x8 v; } r;
  r.h[0] = __float22bfloat162_rn(make_float2(x0.x, x0.y));
  r.h[1] = __float22bfloat162_rn(make_float2(x0.z, x0.w));
  r.h[2] = __float22bfloat162_rn(make_float2(x1.x, x1.y));
  r.h[3] = __float22bfloat162_rn(make_float2(x1.z, x1.w));
  return r.v;
}

#define LGKM0 asm volatile("s_waitcnt lgkmcnt(0)" ::: "memory")
#define VMW8  asm volatile("s_waitcnt vmcnt(8)" ::: "memory")
#define VMW0  asm volatile("s_waitcnt vmcnt(0)" ::: "memory")
#define SBAR  __builtin_amdgcn_s_barrier()

// -------- K0: W fp32 -> bf16 (RNE), 131072 elems --------
__global__ __launch_bounds__(256) void wconv(const float* __restrict__ W,
                                             uint16_t* __restrict__ Wbf) {
  int i = (blockIdx.x * 256 + threadIdx.x) * 8;
  float4 a = *(const float4*)(W + i);
  float4 b = *(const float4*)(W + i + 4);
  *(uint4*)(Wbf + i) = make_uint4(pk_bf16(a.x, a.y), pk_bf16(a.z, a.w),
                                  pk_bf16(b.x, b.y), pk_bf16(b.z, b.w));
}

// -------- K1: GEMM H[m][n] = sum_k A[m][k]*W[n][k], 128x256 tile --------
// grid 500 (M/128), 256 thr, 4 waves. Wave w: n-range [w*64, +64), all 128 m.
// LDS (x2 ring): As fp32 128x32 (8 chunks of 16B; chunk g at slot g^(row&7));
//                Bs bf16 256x32 (4 chunks;          chunk g at slot g^(row&3)).
__global__ __launch_bounds__(256, 2) void gemm_h(const float* __restrict__ A,
                                                 const uint16_t* __restrict__ Wbf,
                                                 uint16_t* __restrict__ H) {
  __shared__ float    As[2][128 * 32];   // 2 x 16 KB
  __shared__ uint16_t Bs[2][256 * 32];   // 2 x 16 KB

  const int tid  = threadIdx.x;
  const int lane = tid & 63;
  const int w    = tid >> 6;
  const int l15  = lane & 15;
  const int quad = lane >> 4;
  const int rm   = blockIdx.x * 128;

  // ---- staging source addresses (swizzle folded into global address) ----
  // A: 4 calls/wave, call i: rows w*32 + i*8 + (lane>>3); slot lane&7 holds
  //    global chunk g = (lane&7) ^ (row&7); 16B = 4 fp32.
  const float* asrc[4];
  char*        aldst[4];
#pragma unroll
  for (int i = 0; i < 4; ++i) {
    int row = w * 32 + i * 8 + (lane >> 3);
    int g   = (lane & 7) ^ (row & 7);
    asrc[i]  = A + (size_t)(rm + row) * Idim + g * 4;
    aldst[i] = (char*)As + w * 4096 + i * 1024;
  }
  // B: 4 calls/wave, call i: rows w*64 + i*16 + (lane>>2); slot lane&3 holds
  //    chunk g = (lane&3) ^ (row&3); 16B = 8 bf16.
  const uint16_t* bsrc[4];
  char*           bldst[4];
#pragma unroll
  for (int i = 0; i < 4; ++i) {
    int row = w * 64 + i * 16 + (lane >> 2);
    int g   = (lane & 3) ^ (row & 3);
    bsrc[i]  = Wbf + (size_t)row * Idim + g * 8;
    bldst[i] = (char*)Bs + w * 4096 + i * 1024;
  }

  // stage k-step t into ring buffer t&1 (8 GLD16 = 8 vmcnt events/wave)
#define STAGE(t_) do {                                                         \
    const int off_ = ((t_) & 1) * 16384;   /* bytes per buffer (both 16KB) */  \
    const int k0_  = (t_) * 32;            /* elements along k */              \
    _Pragma("unroll")                                                          \
    for (int i = 0; i < 4; ++i) GLD16(asrc[i] + k0_, aldst[i] + off_);         \
    _Pragma("unroll")                                                          \
    for (int i = 0; i < 4; ++i) GLD16(bsrc[i] + k0_, bldst[i] + off_);         \
  } while (0)

  f32x4 acc[8][4] = {};

  STAGE(0);                                // prime the ring
#pragma unroll
  for (int t = 0; t < 16; ++t) {
    if (t < 15) { STAGE(t + 1); VMW8; }    // t's 8 retired; t+1's stay in flight
    else        { VMW0; }
    SBAR;                                  // all waves: buf[t&1] fully resident

    const float*    Ab = &As[t & 1][0];
    const uint16_t* Bb = &Bs[t & 1][0];

    // B fragments: n = w*64 + nt*16 + l15, chunk quad at slot quad^(n&3)
    bf16x8 bfr[4];
#pragma unroll
    for (int nt = 0; nt < 4; ++nt) {
      int n = w * 64 + nt * 16 + l15;
      bfr[nt] = *(const bf16x8*)&Bb[n * 32 + ((quad ^ (n & 3)) * 8)];
    }
    // A fragments: m = mt*16 + l15, chunks {2q,2q+1} at slots (2q)^(m&7), s^1
    bf16x8 af[8];
#pragma unroll
    for (int mt = 0; mt < 8; ++mt) {
      int m  = mt * 16 + l15;
      int s0 = (2 * quad) ^ (m & 7);
      float4 x0 = *(const float4*)&Ab[m * 32 + s0 * 4];
      float4 x1 = *(const float4*)&Ab[m * 32 + (s0 ^ 1) * 4];
      af[mt] = cvt8(x0, x1);
      // slot s0 holds chunk 2q, slot s0^1 holds chunk 2q+1 -> k-order correct
    }
#pragma unroll
    for (int mt = 0; mt < 8; ++mt)
#pragma unroll
      for (int nt = 0; nt < 4; ++nt)
        acc[mt][nt] = __builtin_amdgcn_mfma_f32_16x16x32_bf16(af[mt], bfr[nt], acc[mt][nt], 0, 0, 0);

    if (t < 15) {
      LGKM0;                               // own reads of buf[t&1] complete
      SBAR;                                // all waves done -> STAGE(t+2) may overwrite
    }
  }
#undef STAGE

  // epilogue: C/D layout col = lane&15, row = quad*4 + reg
#pragma unroll
  for (int mt = 0; mt < 8; ++mt)
#pragma unroll
    for (int nt = 0; nt < 4; ++nt)
#pragma unroll
      for (int r = 0; r < 4; ++r) {
        int gm = rm + mt * 16 + quad * 4 + r;
        int gn = w * 64 + nt * 16 + l15;
        H[(size_t)gm * Odim + gn] = f2bf(acc[mt][nt][r]);
      }
}

// -------- K2: whole scan in one kernel, h kept in registers --------
// grid 256 = (b, og): block owns 64 o's, all T. 640 thr: c = tid>>4 (40),
// ol = tid&15 (4 o's). Phase1 local scan (h -> regs) -> St(LDS); phase2
// in-LDS combine; phase3 rescan from registers, write Out.
constexpr double dpow(double x, int n) { double r = 1.0; for (int i = 0; i < n; ++i) r *= x; return r; }

__global__ __launch_bounds__(640) void scan_all(const uint16_t* __restrict__ H,
                                                float* __restrict__ Out) {
  constexpr float AL = (float)dpow(0.95, L);
  constexpr float BL = (float)dpow(0.90, L);
  constexpr float WL = (float)((dpow(0.95, L) - dpow(0.90, L)) / (0.95 - 0.90));
  __shared__ float2 St[C][64];

  const int b   = blockIdx.x >> 2;
  const int og  = blockIdx.x & 3;
  const int tid = threadIdx.x;
  const int c   = tid >> 4;
  const int ol  = tid & 15;

  const size_t base = ((size_t)b * T + c * L) * Odim + og * 64 + ol * 4;
  const ushort4* hp = (const ushort4*)(H + base);

  ushort4 hv[L];                        // 25 x 8B = 50 VGPRs, read H once
  // phase 1: local scan, zero init
  {
    float f[4] = {}, u[4] = {};
#pragma unroll
    for (int j = 0; j < L; ++j) {
      hv[j] = hp[j * 64];
      float h0 = bf2f(hv[j].x), h1 = bf2f(hv[j].y), h2 = bf2f(hv[j].z), h3 = bf2f(hv[j].w);
      float n0 = BETA * u[0] + f[0]; f[0] = ALPHA * f[0] + h0; u[0] = n0;
      float n1 = BETA * u[1] + f[1]; f[1] = ALPHA * f[1] + h1; u[1] = n1;
      float n2 = BETA * u[2] + f[2]; f[2] = ALPHA * f[2] + h2; u[2] = n2;
      float n3 = BETA * u[3] + f[3]; f[3] = ALPHA * f[3] + h3; u[3] = n3;
    }
#pragma unroll
    for (int i = 0; i < 4; ++i) St[c][ol * 4 + i] = make_float2(f[i], u[i]);
  }
  __syncthreads();

  // phase 2: combine across chunks in place (St[c] becomes that chunk's init)
  if (tid < 64) {
    float f = 0.f, u = 0.f;
#pragma unroll
    for (int cc = 0; cc < C; ++cc) {
      float2 s = St[cc][tid];
      St[cc][tid] = make_float2(f, u);
      float nu = BL * u + WL * f + s.y;   // uses old f
      f = AL * f + s.x;
      u = nu;
    }
  }
  __syncthreads();

  // phase 3: rescan from registers with chunk inits, write Out
  {
    float f[4], u[4];
#pragma unroll
    for (int i = 0; i < 4; ++i) { float2 s = St[c][ol * 4 + i]; f[i] = s.x; u[i] = s.y; }
    float4* op = (float4*)(Out + base);
#pragma unroll
    for (int j = 0; j < L; ++j) {
      float h0 = bf2f(hv[j].x), h1 = bf2f(hv[j].y), h2 = bf2f(hv[j].z), h3 = bf2f(hv[j].w);
      float4 o4;
      o4.x = BETA * u[0] + f[0]; f[0] = ALPHA * f[0] + h0; u[0] = o4.x;
      o4.y = BETA * u[1] + f[1]; f[1] = ALPHA * f[1] + h1; u[1] = o4.y;
      o4.z = BETA * u[2] + f[2]; f[2] = ALPHA * f[2] + h2; u[2] = o4.z;
      o4.w = BETA * u[3] + f[3]; f[3] = ALPHA * f[3] + h3; u[3] = o4.w;
      op[j * 64] = o4;
    }
  }
}

extern "C" void kernel_launch(void* const* d_in, const int* in_sizes, int n_in,
                              void* d_out, int out_size, void* d_ws, size_t ws_size,
                              hipStream_t stream) {
  const float* A = (const float*)d_in[0];   // (B, T, I) fp32
  const float* W = (const float*)d_in[1];   // (O, I) fp32
  float* Out = (float*)d_out;               // (B, T, O) fp32

  // workspace: H (bf16, 32.77MB) | Wbf (bf16, 0.25MB)
  uint16_t* H   = (uint16_t*)d_ws;
  uint16_t* Wbf = H + (size_t)M * Odim;

  wconv<<<Odim * Idim / (256 * 8), 256, 0, stream>>>(W, Wbf);
  gemm_h<<<M / 128, 256, 0, stream>>>(A, Wbf, H);
  scan_all<<<Bdim * 4, 640, 0, stream>>>(H, Out);
}